// Round 5
// baseline (752.674 us; speedup 1.0000x reference)
//
#include <hip/hip_runtime.h>

// MultiHeadedAttention: B=2, S=2048, D=1024, H=16, DH=64. fp32 in/out.
// R5: R4 structure (k-split attn, fused QKV, big grids) with the spill fixed:
//   __launch_bounds__(256,4) (128-VGPR cap) instead of (256,6) (85-VGPR cap
//   -> scratch spills, VGPR_Count=32, 2x regression in R4).
//   attn: 2048 blocks x 4 waves (2 q-sub x 2 k-split) = 16 waves/CU.
//   QKV fused GEMM: 1536 blocks = 16 waves/CU at (256,4).
#define B_ 2
#define S_ 2048
#define D_ 1024
#define H_ 16
#define DH_ 64

typedef float f32x4 __attribute__((ext_vector_type(4)));
typedef short s16x8 __attribute__((ext_vector_type(8)));
typedef short s16x4 __attribute__((ext_vector_type(4)));
typedef __bf16 bf16x8 __attribute__((ext_vector_type(8)));
typedef unsigned int uint;

// ---- MFMA wrapper: tolerate either builtin signature (short8 or bf16x8) ----
template <typename T>
static __device__ auto mfma_sel(T a, T b, f32x4 c, int)
    -> decltype(__builtin_amdgcn_mfma_f32_16x16x32_bf16(a, b, c, 0, 0, 0)) {
  return __builtin_amdgcn_mfma_f32_16x16x32_bf16(a, b, c, 0, 0, 0);
}
template <typename T>
static __device__ f32x4 mfma_sel(T a, T b, f32x4 c, long) {
  return __builtin_amdgcn_mfma_f32_16x16x32_bf16(
      __builtin_bit_cast(bf16x8, a), __builtin_bit_cast(bf16x8, b), c, 0, 0, 0);
}
static __device__ __forceinline__ f32x4 mfma_bf16(s16x8 a, s16x8 b, f32x4 c) {
  return mfma_sel(a, b, c, 0);
}

static __device__ __forceinline__ short f2bf(float f) {
  unsigned u = __float_as_uint(f);
  u += 0x7fffu + ((u >> 16) & 1u);
  return (short)(u >> 16);
}

template <bool F32>
static __device__ __forceinline__ s16x8 ldfrag(const void* p, size_t off) {
  if constexpr (F32) {
    const float* f = (const float*)p + off;
    f32x4 a = *(const f32x4*)f;
    f32x4 b = *(const f32x4*)(f + 4);
    s16x8 r;
    r[0] = f2bf(a[0]); r[1] = f2bf(a[1]); r[2] = f2bf(a[2]); r[3] = f2bf(a[3]);
    r[4] = f2bf(b[0]); r[5] = f2bf(b[1]); r[6] = f2bf(b[2]); r[7] = f2bf(b[3]);
    return r;
  } else {
    return *(const s16x8*)((const short*)p + off);
  }
}

// ---- mask dtype probe: 0 = byte-bool, 1 = int32 0/1, 2 = fp32 0.0/1.0 ----
__global__ void detect_mask_kernel(const uint* __restrict__ m,
                                   int* __restrict__ flag) {
  int lane = threadIdx.x;
  bool gt1 = false, notf = false;
  for (int i = 0; i < 16; ++i) {
    uint v = m[lane * 16 + i];
    if (v > 1u) gt1 = true;
    if (v != 0u && v != 0x3F800000u) notf = true;
  }
  unsigned long long b1 = __ballot(gt1);
  unsigned long long b2 = __ballot(notf);
  if (lane == 0) {
    int f;
    if (b1 == 0ull) f = 1;
    else if (b2 == 0ull) f = 2;
    else f = 0;
    *flag = f;
  }
}

// ---- mask -> bitmask. bmT[b][kt][q] bit i = (mask[b][q][kt*32+i] != 0) ----
__global__ __launch_bounds__(256) void build_bitmask_kernel(
    const void* __restrict__ mask, const int* __restrict__ flag,
    uint* __restrict__ bmT) {
  int w = blockIdx.x * 256 + threadIdx.x;
  int b = w >> 17;
  int rem = w & 131071;
  int q = rem >> 6;
  int kt = rem & 63;
  int mty = *flag;
  uint bits = 0;
  if (mty == 0) {
    const uint* p = (const uint*)((const unsigned char*)mask +
                                  ((size_t)b * S_ + q) * S_ + (size_t)kt * 32);
#pragma unroll
    for (int i = 0; i < 8; ++i) {
      uint v = p[i];
#pragma unroll
      for (int j = 0; j < 4; ++j)
        if ((v >> (8 * j)) & 0xffu) bits |= 1u << (i * 4 + j);
    }
  } else {
    const uint* p = (const uint*)mask + ((size_t)b * S_ + q) * S_ + kt * 32;
#pragma unroll
    for (int i = 0; i < 32; ++i)
      if (p[i]) bits |= 1u << i;
  }
  bmT[((size_t)b * (S_ / 32) + kt) * S_ + q] = bits;
}

// ---- fp32 -> bf16 bulk convert: query (2048 blk) + Wq/Wk/Wv (512 blk each) ----
__global__ __launch_bounds__(256) void convert_kernel(
    const float* __restrict__ q, const float* __restrict__ wq,
    const float* __restrict__ wk, const float* __restrict__ wv,
    short* __restrict__ qbf, short* __restrict__ wqkv) {
  int bid = blockIdx.x;
  const float* src;
  short* dst;
  size_t base;
  if (bid < 2048) { src = q;  dst = qbf;  base = (size_t)bid * 2048; }
  else if (bid < 2560) { src = wq; dst = wqkv;              base = (size_t)(bid - 2048) * 2048; }
  else if (bid < 3072) { src = wk; dst = wqkv + 1048576;    base = (size_t)(bid - 2560) * 2048; }
  else { src = wv; dst = wqkv + 2097152; base = (size_t)(bid - 3072) * 2048; }
  size_t i = base + (size_t)threadIdx.x * 8;
  f32x4 a = *(const f32x4*)(src + i);
  f32x4 b = *(const f32x4*)(src + i + 4);
  s16x8 r;
  r[0] = f2bf(a[0]); r[1] = f2bf(a[1]); r[2] = f2bf(a[2]); r[3] = f2bf(a[3]);
  r[4] = f2bf(b[0]); r[5] = f2bf(b[1]); r[6] = f2bf(b[2]); r[7] = f2bf(b[3]);
  *(s16x8*)(dst + i) = r;
}

// ---- fused QKV GEMM: C[4096,3072] = qbf @ wqkv^T, routed epilogue ----
__global__ __launch_bounds__(256, 4) void gemm_qkv_kernel(
    const short* __restrict__ A, const short* __restrict__ Bt,
    const float* __restrict__ bq, const float* __restrict__ bk,
    const float* __restrict__ bv, short* __restrict__ q_ws,
    short* __restrict__ k_ws, short* __restrict__ vt_ws) {
  const int tid = threadIdx.x;
  const int lane = tid & 63;
  const int wave = tid >> 6;
  const int l16 = lane & 15;
  const int quad = lane >> 4;
  const int m0 = blockIdx.x * 64 + (wave >> 1) * 32;
  const int n0 = blockIdx.y * 128 + (wave & 1) * 64;

  f32x4 acc[2][4];
#pragma unroll
  for (int i = 0; i < 2; ++i)
#pragma unroll
    for (int j = 0; j < 4; ++j) acc[i][j] = (f32x4){0.f, 0.f, 0.f, 0.f};

  for (int k0 = 0; k0 < 1024; k0 += 32) {
    s16x8 a[2], b[4];
#pragma unroll
    for (int i = 0; i < 2; ++i)
      a[i] = *(const s16x8*)(A + (size_t)(m0 + i * 16 + l16) * 1024 + k0 + quad * 8);
#pragma unroll
    for (int j = 0; j < 4; ++j)
      b[j] = *(const s16x8*)(Bt + (size_t)(n0 + j * 16 + l16) * 1024 + k0 + quad * 8);
#pragma unroll
    for (int i = 0; i < 2; ++i)
#pragma unroll
      for (int j = 0; j < 4; ++j) acc[i][j] = mfma_bf16(a[i], b[j], acc[i][j]);
  }

#pragma unroll
  for (int i = 0; i < 2; ++i) {
#pragma unroll
    for (int j = 0; j < 4; ++j) {
#pragma unroll
      for (int r = 0; r < 4; ++r) {
        int m = m0 + i * 16 + quad * 4 + r;
        int n = n0 + j * 16 + l16;
        int seg = n >> 10, nl = n & 1023;
        float bias = (seg == 0) ? bq[nl] : ((seg == 1) ? bk[nl] : bv[nl]);
        float v = acc[i][j][r] + bias;
        if (seg == 0) v *= 0.125f;
        int bb = m >> 11, s = m & (S_ - 1);
        int hh = nl >> 6, dh = nl & 63;
        if (seg < 2) {
          short* dst = (seg == 0) ? q_ws : k_ws;
          dst[((size_t)(bb * H_ + hh) * S_ + s) * DH_ + dh] = f2bf(v);
        } else {
          vt_ws[((size_t)(bb * H_ + hh) * DH_ + dh) * S_ + s] = f2bf(v);
        }
      }
    }
  }
}

// ---- attention: block = (b,h,qt32); 4 waves = 2 q-sub(16) x 2 k-split ----
__global__ __launch_bounds__(256, 4) void attn_kernel(
    const short* __restrict__ Q, const short* __restrict__ Km,
    const short* __restrict__ Vt, const uint* __restrict__ bmT,
    short* __restrict__ ctx_out) {
  __shared__ float lctx[2][16][64];
  __shared__ float lls[2][16];
  const int tid = threadIdx.x;
  const int lane = tid & 63;
  const int wave = tid >> 6;
  const int l16 = lane & 15;
  const int quad = lane >> 4;
  const int qs = wave & 1;
  const int ks = wave >> 1;
  const int bid = blockIdx.x;
  const int b = bid >> 10;
  const int h = (bid >> 6) & 15;
  const int qt = bid & 63;
  const int qbase = qt * 32 + qs * 16;

  const short* Qh = Q + (size_t)(b * H_ + h) * S_ * DH_;
  const short* Kh = Km + (size_t)(b * H_ + h) * S_ * DH_;
  const short* Vh = Vt + (size_t)(b * H_ + h) * DH_ * S_;
  const uint* bmb = bmT + (size_t)b * (S_ / 32) * S_;

  // Q B-fragments (16 q-rows): B[n=l16][k=quad*8+j]
  s16x8 qf[2];
#pragma unroll
  for (int kf = 0; kf < 2; ++kf)
    qf[kf] = *(const s16x8*)(Qh + (size_t)(qbase + l16) * DH_ + kf * 32 + quad * 8);

  f32x4 ctx[4];
#pragma unroll
  for (int nb = 0; nb < 4; ++nb) ctx[nb] = (f32x4){0.f, 0.f, 0.f, 0.f};
  float ls = 0.f;

  for (int kt = 0; kt < 32; ++kt) {
    const int k0 = ks * 1024 + kt * 32;
    // hoist ALL loads of this iteration for memory-level parallelism
    s16x8 ka[2][2];
#pragma unroll
    for (int kb = 0; kb < 2; ++kb)
#pragma unroll
      for (int kf = 0; kf < 2; ++kf)
        ka[kb][kf] = *(const s16x8*)(Kh + (size_t)(k0 + kb * 16 + l16) * DH_ +
                                     kf * 32 + quad * 8);
    uint w = bmb[(size_t)(k0 >> 5) * S_ + qbase + l16];
    s16x8 vb[4];
#pragma unroll
    for (int nb = 0; nb < 4; ++nb) {
      const short* vrow = Vh + (size_t)(nb * 16 + l16) * S_ + k0 + quad * 4;
      s16x4 lo = *(const s16x4*)(vrow);
      s16x4 hi = *(const s16x4*)(vrow + 16);
      vb[nb] = __builtin_shufflevector(lo, hi, 0, 1, 2, 3, 4, 5, 6, 7);
    }

    // scores^T: C row = key(quad*4+r), col = q(l16)
    f32x4 sc[2];
#pragma unroll
    for (int kb = 0; kb < 2; ++kb) {
      f32x4 t = mfma_bf16(ka[kb][0], qf[0], (f32x4){0.f, 0.f, 0.f, 0.f});
      sc[kb] = mfma_bf16(ka[kb][1], qf[1], t);
    }

    // exp + mask + pack to PV A-operand (k_phys = (j>>2)*16 + quad*4 + (j&3))
    s16x8 pa;
    float sum = 0.f;
#pragma unroll
    for (int kb = 0; kb < 2; ++kb)
#pragma unroll
      for (int r = 0; r < 4; ++r) {
        int bit = (w >> (kb * 16 + quad * 4 + r)) & 1;
        float p = bit ? 0.f : __expf(sc[kb][r]);
        sum += p;
        pa[kb * 4 + r] = f2bf(p);
      }
    ls += sum;

#pragma unroll
    for (int nb = 0; nb < 4; ++nb) ctx[nb] = mfma_bf16(pa, vb[nb], ctx[nb]);
  }

  // reduce l over the 4 quads: every lane ends with row l16's total
  ls += __shfl_xor(ls, 16);
  ls += __shfl_xor(ls, 32);

  if (ks == 1) {
#pragma unroll
    for (int nb = 0; nb < 4; ++nb)
#pragma unroll
      for (int r = 0; r < 4; ++r)
        lctx[qs][quad * 4 + r][nb * 16 + l16] = ctx[nb][r];
    if (lane < 16) lls[qs][l16] = ls;
  }
  __syncthreads();
  if (ks == 0) {
    float lsum = ls + lls[qs][l16];
#pragma unroll
    for (int nb = 0; nb < 4; ++nb)
#pragma unroll
      for (int r = 0; r < 4; ++r)
        ctx[nb][r] += lctx[qs][quad * 4 + r][nb * 16 + l16];
#pragma unroll
    for (int r = 0; r < 4; ++r) {
      float lr = __shfl(lsum, quad * 4 + r);
      float inv = 1.f / lr;
      int srow = qbase + quad * 4 + r;
#pragma unroll
      for (int nb = 0; nb < 4; ++nb) {
        int col = h * DH_ + nb * 16 + l16;
        ctx_out[(size_t)(b * S_ + srow) * D_ + col] = f2bf(ctx[nb][r] * inv);
      }
    }
  }
}

// ---- final GEMM: out[4096,1024] fp32 = ctx_bf16 @ Wo^T + bo ----
__global__ __launch_bounds__(256) void gemm_final_kernel(
    const short* __restrict__ A, const float* __restrict__ Bt,
    const float* __restrict__ bias, float* __restrict__ out) {
  const int tid = threadIdx.x;
  const int lane = tid & 63;
  const int wave = tid >> 6;
  const int l16 = lane & 15;
  const int quad = lane >> 4;
  const int m0 = blockIdx.x * 64 + (wave >> 1) * 32;
  const int n0 = blockIdx.y * 128 + (wave & 1) * 64;

  f32x4 acc[2][4];
#pragma unroll
  for (int i = 0; i < 2; ++i)
#pragma unroll
    for (int j = 0; j < 4; ++j) acc[i][j] = (f32x4){0.f, 0.f, 0.f, 0.f};

  for (int k0 = 0; k0 < 1024; k0 += 32) {
    s16x8 a[2], b[4];
#pragma unroll
    for (int i = 0; i < 2; ++i)
      a[i] = *(const s16x8*)(A + (size_t)(m0 + i * 16 + l16) * 1024 + k0 + quad * 8);
#pragma unroll
    for (int j = 0; j < 4; ++j)
      b[j] = ldfrag<true>(Bt, (size_t)(n0 + j * 16 + l16) * 1024 + k0 + quad * 8);
#pragma unroll
    for (int i = 0; i < 2; ++i)
#pragma unroll
      for (int j = 0; j < 4; ++j) acc[i][j] = mfma_bf16(a[i], b[j], acc[i][j]);
  }

#pragma unroll
  for (int i = 0; i < 2; ++i)
#pragma unroll
    for (int j = 0; j < 4; ++j)
#pragma unroll
      for (int r = 0; r < 4; ++r) {
        int m = m0 + i * 16 + quad * 4 + r;
        int n = n0 + j * 16 + l16;
        out[(size_t)m * 1024 + n] = acc[i][j][r] + bias[n];
      }
}

extern "C" void kernel_launch(void* const* d_in, const int* in_sizes, int n_in,
                              void* d_out, int out_size, void* d_ws,
                              size_t ws_size, hipStream_t stream) {
  const float* query = (const float*)d_in[0];
  const void* mask = d_in[1];
  const float* Wq = (const float*)d_in[2];
  const float* bq = (const float*)d_in[3];
  const float* Wk = (const float*)d_in[4];
  const float* bk = (const float*)d_in[5];
  const float* Wv = (const float*)d_in[6];
  const float* bv = (const float*)d_in[7];
  const float* Wo = (const float*)d_in[8];
  const float* bo = (const float*)d_in[9];

  const size_t NE = (size_t)B_ * S_ * D_;  // 4194304
  short* ws_s = (short*)d_ws;
  short* q_ws = ws_s;             // [B,H,S,DH] bf16
  short* k_ws = ws_s + NE;        // [B,H,S,DH] bf16
  short* vt_ws = ws_s + 2 * NE;   // [B,H,DH,S] bf16
  short* wqkv_bf = ws_s + 3 * NE; // [3072,1024] bf16 (dead after QKV GEMM)
  short* ctx_ws = ws_s + 3 * NE;  // [B,S,D] bf16 -- aliases wqkv (safe)
  // scratch inside d_out (dead before the final GEMM runs):
  short* qbf = (short*)d_out;     // 8 MB query bf16
  uint* bmT = (uint*)(qbf + NE);  // 1 MB bitmask
  int* flag = (int*)(bmT + (size_t)B_ * (S_ / 32) * S_);

  detect_mask_kernel<<<1, 64, 0, stream>>>((const uint*)mask, flag);
  build_bitmask_kernel<<<1024, 256, 0, stream>>>(mask, flag, bmT);
  convert_kernel<<<3584, 256, 0, stream>>>(query, Wq, Wk, Wv, qbf, wqkv_bf);

  gemm_qkv_kernel<<<dim3(64, 24), 256, 0, stream>>>(qbf, wqkv_bf, bq, bk, bv,
                                                    q_ws, k_ws, vt_ws);

  attn_kernel<<<2048, 256, 0, stream>>>(q_ws, k_ws, vt_ws, bmT, ctx_ws);

  gemm_final_kernel<<<dim3(64, 8), 256, 0, stream>>>(ctx_ws, Wo, bo,
                                                     (float*)d_out);
}

// Round 7
// 677.625 us; speedup vs baseline: 1.1108x; 1.1108x over previous
//
#include <hip/hip_runtime.h>

// MultiHeadedAttention: B=2, S=2048, D=1024, H=16, DH=64. fp32 in/out.
// R7: revert to R3's proven-correct base (separate projection GEMMs, no
// k-split, no cross-wave LDS combine, unbounded compiles). Occupancy fixes:
//  - attn: one wave per 16-row q-tile over full K -> 4096 independent waves,
//    1024 blocks = 16 waves/CU (R3: 8). No inter-wave communication at all.
//  - gemm_bt: m-tile 128->64 (acc 2x4), grid 512 blocks = 2 blocks/CU (R3: 1).
#define B_ 2
#define S_ 2048
#define D_ 1024
#define H_ 16
#define DH_ 64

typedef float f32x4 __attribute__((ext_vector_type(4)));
typedef short s16x8 __attribute__((ext_vector_type(8)));
typedef short s16x4 __attribute__((ext_vector_type(4)));
typedef __bf16 bf16x8 __attribute__((ext_vector_type(8)));
typedef unsigned int uint;

// ---- MFMA wrapper: tolerate either builtin signature (short8 or bf16x8) ----
template <typename T>
static __device__ auto mfma_sel(T a, T b, f32x4 c, int)
    -> decltype(__builtin_amdgcn_mfma_f32_16x16x32_bf16(a, b, c, 0, 0, 0)) {
  return __builtin_amdgcn_mfma_f32_16x16x32_bf16(a, b, c, 0, 0, 0);
}
template <typename T>
static __device__ f32x4 mfma_sel(T a, T b, f32x4 c, long) {
  return __builtin_amdgcn_mfma_f32_16x16x32_bf16(
      __builtin_bit_cast(bf16x8, a), __builtin_bit_cast(bf16x8, b), c, 0, 0, 0);
}
static __device__ __forceinline__ f32x4 mfma_bf16(s16x8 a, s16x8 b, f32x4 c) {
  return mfma_sel(a, b, c, 0);
}

static __device__ __forceinline__ short f2bf(float f) {
  unsigned u = __float_as_uint(f);
  u += 0x7fffu + ((u >> 16) & 1u);
  return (short)(u >> 16);
}

template <bool F32>
static __device__ __forceinline__ s16x8 ldfrag(const void* p, size_t off) {
  if constexpr (F32) {
    const float* f = (const float*)p + off;
    f32x4 a = *(const f32x4*)f;
    f32x4 b = *(const f32x4*)(f + 4);
    s16x8 r;
    r[0] = f2bf(a[0]); r[1] = f2bf(a[1]); r[2] = f2bf(a[2]); r[3] = f2bf(a[3]);
    r[4] = f2bf(b[0]); r[5] = f2bf(b[1]); r[6] = f2bf(b[2]); r[7] = f2bf(b[3]);
    return r;
  } else {
    return *(const s16x8*)((const short*)p + off);
  }
}

// ---- mask dtype probe: 0 = byte-bool, 1 = int32 0/1, 2 = fp32 0.0/1.0 ----
__global__ void detect_mask_kernel(const uint* __restrict__ m,
                                   int* __restrict__ flag) {
  int lane = threadIdx.x;
  bool gt1 = false, notf = false;
  for (int i = 0; i < 16; ++i) {
    uint v = m[lane * 16 + i];
    if (v > 1u) gt1 = true;
    if (v != 0u && v != 0x3F800000u) notf = true;
  }
  unsigned long long b1 = __ballot(gt1);
  unsigned long long b2 = __ballot(notf);
  if (lane == 0) {
    int f;
    if (b1 == 0ull) f = 1;
    else if (b2 == 0ull) f = 2;
    else f = 0;
    *flag = f;
  }
}

// ---- mask -> bitmask. bmT[b][kt][q] bit i = (mask[b][q][kt*32+i] != 0) ----
__global__ __launch_bounds__(256) void build_bitmask_kernel(
    const void* __restrict__ mask, const int* __restrict__ flag,
    uint* __restrict__ bmT) {
  int w = blockIdx.x * 256 + threadIdx.x;
  int b = w >> 17;
  int rem = w & 131071;
  int q = rem >> 6;
  int kt = rem & 63;
  int mty = *flag;
  uint bits = 0;
  if (mty == 0) {
    const uint* p = (const uint*)((const unsigned char*)mask +
                                  ((size_t)b * S_ + q) * S_ + (size_t)kt * 32);
#pragma unroll
    for (int i = 0; i < 8; ++i) {
      uint v = p[i];
#pragma unroll
      for (int j = 0; j < 4; ++j)
        if ((v >> (8 * j)) & 0xffu) bits |= 1u << (i * 4 + j);
    }
  } else {
    const uint* p = (const uint*)mask + ((size_t)b * S_ + q) * S_ + kt * 32;
#pragma unroll
    for (int i = 0; i < 32; ++i)
      if (p[i]) bits |= 1u << i;
  }
  bmT[((size_t)b * (S_ / 32) + kt) * S_ + q] = bits;
}

// ---- fp32 -> bf16 bulk convert: query (2048 blk) + Wq/Wk/Wv (512 blk each) ----
__global__ __launch_bounds__(256) void convert_kernel(
    const float* __restrict__ q, const float* __restrict__ wq,
    const float* __restrict__ wk, const float* __restrict__ wv,
    short* __restrict__ qbf, short* __restrict__ wqb, short* __restrict__ wkb,
    short* __restrict__ wvb) {
  int bid = blockIdx.x;
  const float* src;
  short* dst;
  size_t base;
  if (bid < 2048) { src = q;  dst = qbf; base = (size_t)bid * 2048; }
  else if (bid < 2560) { src = wq; dst = wqb; base = (size_t)(bid - 2048) * 2048; }
  else if (bid < 3072) { src = wk; dst = wkb; base = (size_t)(bid - 2560) * 2048; }
  else { src = wv; dst = wvb; base = (size_t)(bid - 3072) * 2048; }
  size_t i = base + (size_t)threadIdx.x * 8;
  f32x4 a = *(const f32x4*)(src + i);
  f32x4 b = *(const f32x4*)(src + i + 4);
  s16x8 r;
  r[0] = f2bf(a[0]); r[1] = f2bf(a[1]); r[2] = f2bf(a[2]); r[3] = f2bf(a[3]);
  r[4] = f2bf(b[0]); r[5] = f2bf(b[1]); r[6] = f2bf(b[2]); r[7] = f2bf(b[3]);
  *(s16x8*)(dst + i) = r;
}

// ---- C[M,N] = A[M,K] @ Bt[N,K]^T, 64x128 tile, epilogue (acc+bias)*scale ----
// mode 0: out[((b*H+h)*S+s)*DH+dh] bf16   (head-major, q/k)
// mode 1: out[((b*H+h)*DH+dh)*S+s] bf16   (head-major transposed, v)
// mode 2: out[m*N+n] fp32                 (final output)
template <bool AF32, bool BF32, bool OUTF32>
__global__ __launch_bounds__(256) void gemm_bt_kernel(
    const void* __restrict__ A, const void* __restrict__ Bt,
    const float* __restrict__ bias, void* __restrict__ out,
    int M, int N, int K, float scale, int mode) {
  const int tid = threadIdx.x;
  const int lane = tid & 63;
  const int wave = tid >> 6;
  const int l16 = lane & 15;
  const int quad = lane >> 4;
  const int m0 = blockIdx.x * 64 + (wave >> 1) * 32;
  const int n0 = blockIdx.y * 128 + (wave & 1) * 64;

  f32x4 acc[2][4];
#pragma unroll
  for (int i = 0; i < 2; ++i)
#pragma unroll
    for (int j = 0; j < 4; ++j) acc[i][j] = (f32x4){0.f, 0.f, 0.f, 0.f};

  for (int k0 = 0; k0 < K; k0 += 32) {
    s16x8 a[2], b[4];
#pragma unroll
    for (int i = 0; i < 2; ++i)
      a[i] = ldfrag<AF32>(A, (size_t)(m0 + i * 16 + l16) * K + k0 + quad * 8);
#pragma unroll
    for (int j = 0; j < 4; ++j)
      b[j] = ldfrag<BF32>(Bt, (size_t)(n0 + j * 16 + l16) * K + k0 + quad * 8);
#pragma unroll
    for (int i = 0; i < 2; ++i)
#pragma unroll
      for (int j = 0; j < 4; ++j) acc[i][j] = mfma_bf16(a[i], b[j], acc[i][j]);
  }

#pragma unroll
  for (int i = 0; i < 2; ++i) {
#pragma unroll
    for (int j = 0; j < 4; ++j) {
#pragma unroll
      for (int r = 0; r < 4; ++r) {
        int m = m0 + i * 16 + quad * 4 + r;
        int n = n0 + j * 16 + l16;
        float v = (acc[i][j][r] + bias[n]) * scale;
        size_t idx;
        if (mode == 2) {
          idx = (size_t)m * N + n;
        } else {
          int bb = m >> 11, s = m & (S_ - 1);
          int h = n >> 6, dh = n & (DH_ - 1);
          if (mode == 0)
            idx = ((size_t)(bb * H_ + h) * S_ + s) * DH_ + dh;
          else
            idx = ((size_t)(bb * H_ + h) * DH_ + dh) * S_ + s;
        }
        if constexpr (OUTF32)
          ((float*)out)[idx] = v;
        else
          ((short*)out)[idx] = f2bf(v);
      }
    }
  }
}

// ---- attention: one INDEPENDENT wave per (b, h, 16-row q-tile), full K ----
// No LDS, no inter-wave communication. S^T = K*Q^T register-P trick (R3).
__global__ __launch_bounds__(256) void attn_kernel(
    const short* __restrict__ Q, const short* __restrict__ Km,
    const short* __restrict__ Vt, const uint* __restrict__ bmT,
    short* __restrict__ ctx_out) {
  const int tid = threadIdx.x;
  const int lane = tid & 63;
  const int wave = tid >> 6;
  const int l16 = lane & 15;
  const int quad = lane >> 4;
  const int task = blockIdx.x * 4 + wave;  // [0, 4096)
  const int b = task >> 11;
  const int h = (task >> 7) & 15;
  const int qt = task & 127;
  const int qbase = qt * 16;

  const short* Qh = Q + (size_t)(b * H_ + h) * S_ * DH_;
  const short* Kh = Km + (size_t)(b * H_ + h) * S_ * DH_;
  const short* Vh = Vt + (size_t)(b * H_ + h) * DH_ * S_;
  const uint* bmb = bmT + (size_t)b * (S_ / 32) * S_;

  // Q B-fragments (16 q-rows): B[n=l16][k=quad*8+j]
  s16x8 qf[2];
#pragma unroll
  for (int kf = 0; kf < 2; ++kf)
    qf[kf] = *(const s16x8*)(Qh + (size_t)(qbase + l16) * DH_ + kf * 32 + quad * 8);

  f32x4 ctx[4];
#pragma unroll
  for (int nb = 0; nb < 4; ++nb) ctx[nb] = (f32x4){0.f, 0.f, 0.f, 0.f};
  float ls = 0.f;

  for (int kt = 0; kt < S_ / 32; ++kt) {
    const int k0 = kt * 32;
    // hoist all loads of this iteration for memory-level parallelism
    s16x8 ka[2][2];
#pragma unroll
    for (int kb = 0; kb < 2; ++kb)
#pragma unroll
      for (int kf = 0; kf < 2; ++kf)
        ka[kb][kf] = *(const s16x8*)(Kh + (size_t)(k0 + kb * 16 + l16) * DH_ +
                                     kf * 32 + quad * 8);
    uint w = bmb[(size_t)kt * S_ + qbase + l16];
    s16x8 vb[4];
#pragma unroll
    for (int nb = 0; nb < 4; ++nb) {
      const short* vrow = Vh + (size_t)(nb * 16 + l16) * S_ + k0 + quad * 4;
      s16x4 lo = *(const s16x4*)(vrow);
      s16x4 hi = *(const s16x4*)(vrow + 16);
      vb[nb] = __builtin_shufflevector(lo, hi, 0, 1, 2, 3, 4, 5, 6, 7);
    }

    // scores^T: C row = key(quad*4+r), col = q(l16)
    f32x4 sc[2];
#pragma unroll
    for (int kb = 0; kb < 2; ++kb) {
      f32x4 t = mfma_bf16(ka[kb][0], qf[0], (f32x4){0.f, 0.f, 0.f, 0.f});
      sc[kb] = mfma_bf16(ka[kb][1], qf[1], t);
    }

    // exp + mask + pack to PV A-operand (k_phys = (j>>2)*16 + quad*4 + (j&3))
    s16x8 pa;
    float sum = 0.f;
#pragma unroll
    for (int kb = 0; kb < 2; ++kb)
#pragma unroll
      for (int r = 0; r < 4; ++r) {
        int bit = (w >> (kb * 16 + quad * 4 + r)) & 1;
        float p = bit ? 0.f : __expf(sc[kb][r]);
        sum += p;
        pa[kb * 4 + r] = f2bf(p);
      }
    ls += sum;

#pragma unroll
    for (int nb = 0; nb < 4; ++nb) ctx[nb] = mfma_bf16(pa, vb[nb], ctx[nb]);
  }

  // reduce l over the 4 quads: every lane ends with row l16's total
  ls += __shfl_xor(ls, 16);
  ls += __shfl_xor(ls, 32);

  // epilogue: ctx C-layout row = q(quad*4+r), col = dh(l16)
#pragma unroll
  for (int r = 0; r < 4; ++r) {
    float lr = __shfl(ls, quad * 4 + r);
    float inv = 1.f / lr;
    int srow = qbase + quad * 4 + r;
#pragma unroll
    for (int nb = 0; nb < 4; ++nb) {
      int col = h * DH_ + nb * 16 + l16;
      ctx_out[(size_t)(b * S_ + srow) * D_ + col] = f2bf(ctx[nb][r] * inv);
    }
  }
}

extern "C" void kernel_launch(void* const* d_in, const int* in_sizes, int n_in,
                              void* d_out, int out_size, void* d_ws,
                              size_t ws_size, hipStream_t stream) {
  const float* query = (const float*)d_in[0];
  const void* mask = d_in[1];
  const float* Wq = (const float*)d_in[2];
  const float* bq = (const float*)d_in[3];
  const float* Wk = (const float*)d_in[4];
  const float* bk = (const float*)d_in[5];
  const float* Wv = (const float*)d_in[6];
  const float* bv = (const float*)d_in[7];
  const float* Wo = (const float*)d_in[8];
  const float* bo = (const float*)d_in[9];

  const size_t NE = (size_t)B_ * S_ * D_;  // 4194304
  short* ws_s = (short*)d_ws;
  short* q_ws = ws_s;             // [B,H,S,DH] bf16
  short* k_ws = ws_s + NE;        // [B,H,S,DH] bf16
  short* vt_ws = ws_s + 2 * NE;   // [B,H,DH,S] bf16
  short* wq_bf = ws_s + 3 * NE;   // weights bf16 (dead after projections)
  short* wk_bf = wq_bf + NE / 4;
  short* wv_bf = wq_bf + NE / 2;
  short* ctx_ws = ws_s + 3 * NE;  // [B,S,D] bf16 -- aliases wq/wk/wv (safe:
                                  // attn runs after all projections)
  // scratch inside d_out (dead before the final GEMM runs):
  short* qbf = (short*)d_out;     // 8 MB query bf16
  uint* bmT = (uint*)(qbf + NE);  // 1 MB bitmask
  int* flag = (int*)(bmT + (size_t)B_ * (S_ / 32) * S_);

  detect_mask_kernel<<<1, 64, 0, stream>>>((const uint*)mask, flag);
  build_bitmask_kernel<<<1024, 256, 0, stream>>>(mask, flag, bmT);
  convert_kernel<<<3584, 256, 0, stream>>>(query, Wq, Wk, Wv, qbf, wq_bf, wk_bf,
                                           wv_bf);

  dim3 gg(B_ * S_ / 64, D_ / 128), gb(256);
  const int M = B_ * S_;
  gemm_bt_kernel<false, false, false><<<gg, gb, 0, stream>>>(
      qbf, wq_bf, bq, q_ws, M, D_, D_, 0.125f, 0);
  gemm_bt_kernel<false, false, false><<<gg, gb, 0, stream>>>(
      qbf, wk_bf, bk, k_ws, M, D_, D_, 1.0f, 0);
  gemm_bt_kernel<false, false, false><<<gg, gb, 0, stream>>>(
      qbf, wv_bf, bv, vt_ws, M, D_, D_, 1.0f, 1);

  attn_kernel<<<1024, 256, 0, stream>>>(q_ws, k_ws, vt_ws, bmT, ctx_ws);

  gemm_bt_kernel<false, true, true><<<gg, gb, 0, stream>>>(
      ctx_ws, Wo, bo, d_out, M, D_, D_, 1.0f, 2);
}

// Round 8
// 300.508 us; speedup vs baseline: 2.5047x; 2.2549x over previous
//
#include <hip/hip_runtime.h>

// MultiHeadedAttention: B=2, S=2048, D=1024, H=16, DH=64. fp32 in/out.
// R8: kill serialized-load latency with global_load_lds (async global->LDS,
// no dest VGPRs -> MLP lives in the HW queue, not the register allocator).
//  - K/V stored in FRAGMENT ORDER per (bh, 32-key tile): staging is one
//    contiguous 4KB load per tile; LDS reads are consecutive-lane b128.
//  - attn: 1024 blocks x 4 waves (each 16 q-rows, sharing staged K/V, no
//    cross-wave dataflow). m97 2-barrier loop.
//  - QKV fused GEMM: 128x128 tile, BK=32, staged A/B (frag-ordered globals
//    written by convert_kernel), 768 blocks = 3/CU (m97 regime).
//  - final GEMM: unchanged R7 (known-good).
#define B_ 2
#define S_ 2048
#define D_ 1024
#define H_ 16
#define DH_ 64

typedef float f32x4 __attribute__((ext_vector_type(4)));
typedef short s16x8 __attribute__((ext_vector_type(8)));
typedef __bf16 bf16x8 __attribute__((ext_vector_type(8)));
typedef unsigned int uint;

// ---- MFMA wrapper: tolerate either builtin signature (short8 or bf16x8) ----
template <typename T>
static __device__ auto mfma_sel(T a, T b, f32x4 c, int)
    -> decltype(__builtin_amdgcn_mfma_f32_16x16x32_bf16(a, b, c, 0, 0, 0)) {
  return __builtin_amdgcn_mfma_f32_16x16x32_bf16(a, b, c, 0, 0, 0);
}
template <typename T>
static __device__ f32x4 mfma_sel(T a, T b, f32x4 c, long) {
  return __builtin_amdgcn_mfma_f32_16x16x32_bf16(
      __builtin_bit_cast(bf16x8, a), __builtin_bit_cast(bf16x8, b), c, 0, 0, 0);
}
static __device__ __forceinline__ f32x4 mfma_bf16(s16x8 a, s16x8 b, f32x4 c) {
  return mfma_sel(a, b, c, 0);
}

static __device__ __forceinline__ short f2bf(float f) {
  unsigned u = __float_as_uint(f);
  u += 0x7fffu + ((u >> 16) & 1u);
  return (short)(u >> 16);
}

template <bool F32>
static __device__ __forceinline__ s16x8 ldfrag(const void* p, size_t off) {
  if constexpr (F32) {
    const float* f = (const float*)p + off;
    f32x4 a = *(const f32x4*)f;
    f32x4 b = *(const f32x4*)(f + 4);
    s16x8 r;
    r[0] = f2bf(a[0]); r[1] = f2bf(a[1]); r[2] = f2bf(a[2]); r[3] = f2bf(a[3]);
    r[4] = f2bf(b[0]); r[5] = f2bf(b[1]); r[6] = f2bf(b[2]); r[7] = f2bf(b[3]);
    return r;
  } else {
    return *(const s16x8*)((const short*)p + off);
  }
}

// ---- async 16B global -> LDS (wave-uniform base + lane*16 on the LDS side) --
static __device__ __forceinline__ void async16(const short* g, short* l) {
  __builtin_amdgcn_global_load_lds(
      (const __attribute__((address_space(1))) unsigned int*)g,
      (__attribute__((address_space(3))) unsigned int*)l, 16, 0, 0);
}

// ---- mask dtype probe: 0 = byte-bool, 1 = int32 0/1, 2 = fp32 0.0/1.0 ----
__global__ void detect_mask_kernel(const uint* __restrict__ m,
                                   int* __restrict__ flag) {
  int lane = threadIdx.x;
  bool gt1 = false, notf = false;
  for (int i = 0; i < 16; ++i) {
    uint v = m[lane * 16 + i];
    if (v > 1u) gt1 = true;
    if (v != 0u && v != 0x3F800000u) notf = true;
  }
  unsigned long long b1 = __ballot(gt1);
  unsigned long long b2 = __ballot(notf);
  if (lane == 0) {
    int f;
    if (b1 == 0ull) f = 1;
    else if (b2 == 0ull) f = 2;
    else f = 0;
    *flag = f;
  }
}

// ---- mask -> bitmask. bmT[b][kt][q] bit i = (mask[b][q][kt*32+i] != 0) ----
__global__ __launch_bounds__(256) void build_bitmask_kernel(
    const void* __restrict__ mask, const int* __restrict__ flag,
    uint* __restrict__ bmT) {
  int w = blockIdx.x * 256 + threadIdx.x;
  int b = w >> 17;
  int rem = w & 131071;
  int q = rem >> 6;
  int kt = rem & 63;
  int mty = *flag;
  uint bits = 0;
  if (mty == 0) {
    const uint* p = (const uint*)((const unsigned char*)mask +
                                  ((size_t)b * S_ + q) * S_ + (size_t)kt * 32);
#pragma unroll
    for (int i = 0; i < 8; ++i) {
      uint v = p[i];
#pragma unroll
      for (int j = 0; j < 4; ++j)
        if ((v >> (8 * j)) & 0xffu) bits |= 1u << (i * 4 + j);
    }
  } else {
    const uint* p = (const uint*)mask + ((size_t)b * S_ + q) * S_ + kt * 32;
#pragma unroll
    for (int i = 0; i < 32; ++i)
      if (p[i]) bits |= 1u << i;
  }
  bmT[((size_t)b * (S_ / 32) + kt) * S_ + q] = bits;
}

// ---- fp32 -> bf16 convert into FRAGMENT-ORDER layout -----------------------
// frag chunk for (row, k): chunk = (row>>4)*32 + (k>>5) groups of 64 lanes;
// lane = ((k>>3)&3)*16 + (row&15); element = k&7. 16B per chunk.
__global__ __launch_bounds__(256) void convert_kernel(
    const float* __restrict__ q, const float* __restrict__ wq,
    const float* __restrict__ wk, const float* __restrict__ wv,
    short* __restrict__ qbf, short* __restrict__ wqkv) {
  int bid = blockIdx.x;
  int t = threadIdx.x;
  const float* src;
  short* dst;
  int rowbase, seg;
  if (bid < 2048)      { src = q;  dst = qbf;  rowbase = bid * 2;          seg = -1; }
  else if (bid < 2560) { src = wq; dst = wqkv; rowbase = (bid - 2048) * 2; seg = 0; }
  else if (bid < 3072) { src = wk; dst = wqkv; rowbase = (bid - 2560) * 2; seg = 1; }
  else                 { src = wv; dst = wqkv; rowbase = (bid - 3072) * 2; seg = 2; }
  int rl = rowbase + (t >> 7);   // local row (2 rows per block)
  int k = (t & 127) * 8;
  const float* s8 = src + (size_t)rl * 1024 + k;
  f32x4 a = *(const f32x4*)s8;
  f32x4 b = *(const f32x4*)(s8 + 4);
  s16x8 r;
  r[0] = f2bf(a[0]); r[1] = f2bf(a[1]); r[2] = f2bf(a[2]); r[3] = f2bf(a[3]);
  r[4] = f2bf(b[0]); r[5] = f2bf(b[1]); r[6] = f2bf(b[2]); r[7] = f2bf(b[3]);
  int grow = (seg < 0) ? rl : (seg * 1024 + rl);
  size_t chunk = ((size_t)(grow >> 4) * 32 + (k >> 5)) * 64 +
                 ((k >> 3) & 3) * 16 + (grow & 15);
  *(s16x8*)(dst + chunk * 8) = r;
}

// ---- fused QKV GEMM, m97-style staged: C[4096,3072] = qbf @ wqkv^T ---------
// A, Bt in fragment order. Epilogue routes: q -> q_ws row-major (scale 1/8),
// k -> KF fragment order, v -> VF fragment order (PV-permuted).
__global__ __launch_bounds__(256) void gemm_qkv_kernel(
    const short* __restrict__ A, const short* __restrict__ Bt,
    const float* __restrict__ bq, const float* __restrict__ bk,
    const float* __restrict__ bv, short* __restrict__ q_ws,
    short* __restrict__ KF, short* __restrict__ VF) {
  __shared__ short lds[8192];  // A tile 4096 shorts, B tile 4096 shorts
  const int tid = threadIdx.x;
  const int lane = tid & 63;
  const int wave = tid >> 6;
  const int l16 = lane & 15;
  const int quad = lane >> 4;
  const int mb0 = blockIdx.x * 8;
  const int nb0 = blockIdx.y * 8;
  const int m0 = blockIdx.x * 128 + (wave >> 1) * 64;
  const int n0 = blockIdx.y * 128 + (wave & 1) * 64;
  const int g = tid >> 6, c = tid & 63;

  f32x4 acc[4][4];
#pragma unroll
  for (int i = 0; i < 4; ++i)
#pragma unroll
    for (int j = 0; j < 4; ++j) acc[i][j] = (f32x4){0.f, 0.f, 0.f, 0.f};

  for (int kb = 0; kb < 32; ++kb) {
    async16(A + (((size_t)(mb0 + g) * 32 + kb) * 64 + c) * 8, lds + tid * 8);
    async16(A + (((size_t)(mb0 + g + 4) * 32 + kb) * 64 + c) * 8,
            lds + 2048 + tid * 8);
    async16(Bt + (((size_t)(nb0 + g) * 32 + kb) * 64 + c) * 8,
            lds + 4096 + tid * 8);
    async16(Bt + (((size_t)(nb0 + g + 4) * 32 + kb) * 64 + c) * 8,
            lds + 6144 + tid * 8);
    __syncthreads();
    s16x8 a[4], b[4];
#pragma unroll
    for (int i = 0; i < 4; ++i)
      a[i] = *(const s16x8*)(lds + (((wave >> 1) * 4 + i) * 64 + lane) * 8);
#pragma unroll
    for (int j = 0; j < 4; ++j)
      b[j] = *(const s16x8*)(lds + 4096 + (((wave & 1) * 4 + j) * 64 + lane) * 8);
#pragma unroll
    for (int i = 0; i < 4; ++i)
#pragma unroll
      for (int j = 0; j < 4; ++j) acc[i][j] = mfma_bf16(a[i], b[j], acc[i][j]);
    __syncthreads();
  }

#pragma unroll
  for (int i = 0; i < 4; ++i) {
#pragma unroll
    for (int j = 0; j < 4; ++j) {
#pragma unroll
      for (int r = 0; r < 4; ++r) {
        int m = m0 + i * 16 + quad * 4 + r;
        int n = n0 + j * 16 + l16;
        int seg = n >> 10, nl = n & 1023;
        float bias = (seg == 0) ? bq[nl] : ((seg == 1) ? bk[nl] : bv[nl]);
        float v = acc[i][j][r] + bias;
        if (seg == 0) v *= 0.125f;
        int bb = m >> 11, s = m & (S_ - 1);
        int hh = nl >> 6, dh = nl & 63;
        int bh = bb * H_ + hh;
        short bv16 = f2bf(v);
        if (seg == 0) {
          q_ws[((size_t)bh * S_ + s) * DH_ + dh] = bv16;
        } else if (seg == 1) {
          int kt = s >> 5, r5 = s & 31;
          int kkb = r5 >> 4, kl16 = r5 & 15;
          int kf = dh >> 5, qd = (dh >> 3) & 3, e = dh & 7;
          KF[(size_t)bh * 131072 +
             ((size_t)kt * 256 + (kkb * 2 + kf) * 64 + qd * 16 + kl16) * 8 + e] = bv16;
        } else {
          int kt = s >> 5, ko = s & 31;
          int hi = ko >> 4, qd = (ko >> 2) & 3, j4 = ko & 3;
          int nb = dh >> 4, vl16 = dh & 15, e = hi * 4 + j4;
          VF[(size_t)bh * 131072 +
             ((size_t)kt * 256 + nb * 64 + qd * 16 + vl16) * 8 + e] = bv16;
        }
      }
    }
  }
}

// ---- attention: 1024 blocks x 4 waves; staged fragment-order K/V tiles -----
__global__ __launch_bounds__(256) void attn_kernel(
    const short* __restrict__ Q, const short* __restrict__ KF,
    const short* __restrict__ VF, const uint* __restrict__ bmT,
    short* __restrict__ ctx_out) {
  __shared__ short lds[4096];  // K tile [0:2048), V tile [2048:4096) shorts
  const int tid = threadIdx.x;
  const int lane = tid & 63;
  const int wave = tid >> 6;
  const int l16 = lane & 15;
  const int quad = lane >> 4;
  const int bid = blockIdx.x;
  const int bh = bid >> 5;    // 0..31
  const int qt64 = bid & 31;
  const int b = bh >> 4;
  const int h = bh & 15;
  const int qbase = qt64 * 64 + wave * 16;

  const short* Qh = Q + (size_t)bh * S_ * DH_;
  const short* KFb = KF + (size_t)bh * 131072;
  const short* VFb = VF + (size_t)bh * 131072;
  const uint* bmb = bmT + (size_t)b * (S_ / 32) * S_;

  // Q B-fragments (row-major q_ws, loaded once): B[n=l16][k=quad*8+j]
  s16x8 qf[2];
#pragma unroll
  for (int kf = 0; kf < 2; ++kf)
    qf[kf] = *(const s16x8*)(Qh + (size_t)(qbase + l16) * DH_ + kf * 32 + quad * 8);

  f32x4 ctx[4];
#pragma unroll
  for (int nb = 0; nb < 4; ++nb) ctx[nb] = (f32x4){0.f, 0.f, 0.f, 0.f};
  float ls = 0.f;

  uint w_cur = bmb[qbase + l16];  // kt = 0 mask word
  for (int kt = 0; kt < S_ / 32; ++kt) {
    // stage tile kt (all waves passed previous trailing barrier)
    async16(KFb + (size_t)kt * 2048 + tid * 8, lds + tid * 8);
    async16(VFb + (size_t)kt * 2048 + tid * 8, lds + 2048 + tid * 8);
    int ktn = (kt < S_ / 32 - 1) ? kt + 1 : kt;
    uint w_nxt = bmb[(size_t)ktn * S_ + qbase + l16];
    __syncthreads();  // drains vmcnt -> tile ready

    s16x8 ka[2][2], vb[4];
#pragma unroll
    for (int kb = 0; kb < 2; ++kb)
#pragma unroll
      for (int kf = 0; kf < 2; ++kf)
        ka[kb][kf] = *(const s16x8*)(lds + ((kb * 2 + kf) * 64 + lane) * 8);
#pragma unroll
    for (int nb = 0; nb < 4; ++nb)
      vb[nb] = *(const s16x8*)(lds + 2048 + (nb * 64 + lane) * 8);

    // scores^T: C row = key(quad*4+r), col = q(l16)
    f32x4 sc[2];
#pragma unroll
    for (int kb = 0; kb < 2; ++kb) {
      f32x4 t = mfma_bf16(ka[kb][0], qf[0], (f32x4){0.f, 0.f, 0.f, 0.f});
      sc[kb] = mfma_bf16(ka[kb][1], qf[1], t);
    }

    // exp + mask + pack to PV A-operand (k_phys = (j>>2)*16 + quad*4 + (j&3))
    s16x8 pa;
    float sum = 0.f;
#pragma unroll
    for (int kb = 0; kb < 2; ++kb)
#pragma unroll
      for (int r = 0; r < 4; ++r) {
        int bit = (w_cur >> (kb * 16 + quad * 4 + r)) & 1;
        float p = bit ? 0.f : __expf(sc[kb][r]);
        sum += p;
        pa[kb * 4 + r] = f2bf(p);
      }
    ls += sum;

#pragma unroll
    for (int nb = 0; nb < 4; ++nb) ctx[nb] = mfma_bf16(pa, vb[nb], ctx[nb]);
    __syncthreads();  // all waves done reading before next overwrite
    w_cur = w_nxt;
  }

  // reduce l over the 4 quads: every lane ends with row l16's total
  ls += __shfl_xor(ls, 16);
  ls += __shfl_xor(ls, 32);

  // epilogue: ctx C-layout row = q(quad*4+r), col = dh(l16); row-major out
#pragma unroll
  for (int r = 0; r < 4; ++r) {
    float lr = __shfl(ls, quad * 4 + r);
    float inv = 1.f / lr;
    int srow = qbase + quad * 4 + r;
#pragma unroll
    for (int nb = 0; nb < 4; ++nb) {
      int col = h * DH_ + nb * 16 + l16;
      ctx_out[(size_t)(b * S_ + srow) * D_ + col] = f2bf(ctx[nb][r] * inv);
    }
  }
}

// ---- final GEMM: out[4096,1024] fp32 = ctx_bf16 @ Wo^T + bo (R7, unchanged) -
__global__ __launch_bounds__(256) void gemm_final_kernel(
    const short* __restrict__ A, const float* __restrict__ Bt,
    const float* __restrict__ bias, float* __restrict__ out) {
  const int tid = threadIdx.x;
  const int lane = tid & 63;
  const int wave = tid >> 6;
  const int l16 = lane & 15;
  const int quad = lane >> 4;
  const int m0 = blockIdx.x * 64 + (wave >> 1) * 32;
  const int n0 = blockIdx.y * 128 + (wave & 1) * 64;

  f32x4 acc[2][4];
#pragma unroll
  for (int i = 0; i < 2; ++i)
#pragma unroll
    for (int j = 0; j < 4; ++j) acc[i][j] = (f32x4){0.f, 0.f, 0.f, 0.f};

  for (int k0 = 0; k0 < 1024; k0 += 32) {
    s16x8 a[2], b[4];
#pragma unroll
    for (int i = 0; i < 2; ++i)
      a[i] = *(const s16x8*)(A + (size_t)(m0 + i * 16 + l16) * 1024 + k0 + quad * 8);
#pragma unroll
    for (int j = 0; j < 4; ++j)
      b[j] = ldfrag<true>(Bt, (size_t)(n0 + j * 16 + l16) * 1024 + k0 + quad * 8);
#pragma unroll
    for (int i = 0; i < 2; ++i)
#pragma unroll
      for (int j = 0; j < 4; ++j) acc[i][j] = mfma_bf16(a[i], b[j], acc[i][j]);
  }

#pragma unroll
  for (int i = 0; i < 2; ++i)
#pragma unroll
    for (int j = 0; j < 4; ++j)
#pragma unroll
      for (int r = 0; r < 4; ++r) {
        int m = m0 + i * 16 + quad * 4 + r;
        int n = n0 + j * 16 + l16;
        out[(size_t)m * 1024 + n] = acc[i][j][r] + bias[n];
      }
}

extern "C" void kernel_launch(void* const* d_in, const int* in_sizes, int n_in,
                              void* d_out, int out_size, void* d_ws,
                              size_t ws_size, hipStream_t stream) {
  const float* query = (const float*)d_in[0];
  const void* mask = d_in[1];
  const float* Wq = (const float*)d_in[2];
  const float* bq = (const float*)d_in[3];
  const float* Wk = (const float*)d_in[4];
  const float* bk = (const float*)d_in[5];
  const float* Wv = (const float*)d_in[6];
  const float* bv = (const float*)d_in[7];
  const float* Wo = (const float*)d_in[8];
  const float* bo = (const float*)d_in[9];

  const size_t NE = (size_t)B_ * S_ * D_;  // 4194304
  short* ws_s = (short*)d_ws;
  short* q_ws = ws_s;             // [B,H,S,DH] bf16 row-major (8 MB)
  short* KF = ws_s + NE;          // K fragment-order (8 MB)
  short* VF = ws_s + 2 * NE;      // V fragment-order, PV-permuted (8 MB)
  short* ctx_ws = ws_s + 3 * NE;  // [B,S,D] bf16 row-major (8 MB)
  // scratch inside d_out (all dead before the final GEMM runs):
  short* qbf = (short*)d_out;          // [0:8M)  query bf16, fragment order
  short* wqkv = qbf + NE;              // [8:14M) Wq|Wk|Wv bf16, fragment order
  uint* bmT = (uint*)(wqkv + 3145728); // [14:15M) bitmask
  int* flag = (int*)(bmT + 262144);

  detect_mask_kernel<<<1, 64, 0, stream>>>((const uint*)mask, flag);
  build_bitmask_kernel<<<1024, 256, 0, stream>>>(mask, flag, bmT);
  convert_kernel<<<3584, 256, 0, stream>>>(query, Wq, Wk, Wv, qbf, wqkv);

  gemm_qkv_kernel<<<dim3(32, 24), 256, 0, stream>>>(qbf, wqkv, bq, bk, bv,
                                                    q_ws, KF, VF);

  attn_kernel<<<1024, 256, 0, stream>>>(q_ws, KF, VF, bmT, ctx_ws);

  gemm_final_kernel<<<dim3(64, 8), 256, 0, stream>>>(ctx_ws, Wo, bo,
                                                     (float*)d_out);
}

// Round 9
// 259.987 us; speedup vs baseline: 2.8950x; 1.1559x over previous
//
#include <hip/hip_runtime.h>

// MultiHeadedAttention: B=2, S=2048, D=1024, H=16, DH=64. fp32 in/out.
// R9: R8 + final GEMM m97-ized (it was the new #1 at 80us, VGPR 64,
// MfmaUtil 4% -- serialized loads + fp32 Wo fragment converts in-loop).
//  - convert_wo (after attn, into dead q_ws region): Wo fp32 -> bf16.
//  - gemm_final: 128x128 tile, BK=32, global_load_lds staging. A(ctx)/B(Wo)
//    stay ROW-MAJOR: per-lane global gather (16 rows x 64B contiguous per
//    wave) lands fragment-ordered in LDS (conflict-free b128 reads).
#define B_ 2
#define S_ 2048
#define D_ 1024
#define H_ 16
#define DH_ 64

typedef float f32x4 __attribute__((ext_vector_type(4)));
typedef short s16x8 __attribute__((ext_vector_type(8)));
typedef __bf16 bf16x8 __attribute__((ext_vector_type(8)));
typedef unsigned int uint;

// ---- MFMA wrapper: tolerate either builtin signature (short8 or bf16x8) ----
template <typename T>
static __device__ auto mfma_sel(T a, T b, f32x4 c, int)
    -> decltype(__builtin_amdgcn_mfma_f32_16x16x32_bf16(a, b, c, 0, 0, 0)) {
  return __builtin_amdgcn_mfma_f32_16x16x32_bf16(a, b, c, 0, 0, 0);
}
template <typename T>
static __device__ f32x4 mfma_sel(T a, T b, f32x4 c, long) {
  return __builtin_amdgcn_mfma_f32_16x16x32_bf16(
      __builtin_bit_cast(bf16x8, a), __builtin_bit_cast(bf16x8, b), c, 0, 0, 0);
}
static __device__ __forceinline__ f32x4 mfma_bf16(s16x8 a, s16x8 b, f32x4 c) {
  return mfma_sel(a, b, c, 0);
}

static __device__ __forceinline__ short f2bf(float f) {
  unsigned u = __float_as_uint(f);
  u += 0x7fffu + ((u >> 16) & 1u);
  return (short)(u >> 16);
}

// ---- async 16B global -> LDS (per-lane GLOBAL addr ok; LDS side = base+lane*16)
static __device__ __forceinline__ void async16(const short* g, short* l) {
  __builtin_amdgcn_global_load_lds(
      (const __attribute__((address_space(1))) unsigned int*)g,
      (__attribute__((address_space(3))) unsigned int*)l, 16, 0, 0);
}

// ---- mask dtype probe: 0 = byte-bool, 1 = int32 0/1, 2 = fp32 0.0/1.0 ----
__global__ void detect_mask_kernel(const uint* __restrict__ m,
                                   int* __restrict__ flag) {
  int lane = threadIdx.x;
  bool gt1 = false, notf = false;
  for (int i = 0; i < 16; ++i) {
    uint v = m[lane * 16 + i];
    if (v > 1u) gt1 = true;
    if (v != 0u && v != 0x3F800000u) notf = true;
  }
  unsigned long long b1 = __ballot(gt1);
  unsigned long long b2 = __ballot(notf);
  if (lane == 0) {
    int f;
    if (b1 == 0ull) f = 1;
    else if (b2 == 0ull) f = 2;
    else f = 0;
    *flag = f;
  }
}

// ---- mask -> bitmask. bmT[b][kt][q] bit i = (mask[b][q][kt*32+i] != 0) ----
__global__ __launch_bounds__(256) void build_bitmask_kernel(
    const void* __restrict__ mask, const int* __restrict__ flag,
    uint* __restrict__ bmT) {
  int w = blockIdx.x * 256 + threadIdx.x;
  int b = w >> 17;
  int rem = w & 131071;
  int q = rem >> 6;
  int kt = rem & 63;
  int mty = *flag;
  uint bits = 0;
  if (mty == 0) {
    const uint* p = (const uint*)((const unsigned char*)mask +
                                  ((size_t)b * S_ + q) * S_ + (size_t)kt * 32);
#pragma unroll
    for (int i = 0; i < 8; ++i) {
      uint v = p[i];
#pragma unroll
      for (int j = 0; j < 4; ++j)
        if ((v >> (8 * j)) & 0xffu) bits |= 1u << (i * 4 + j);
    }
  } else {
    const uint* p = (const uint*)mask + ((size_t)b * S_ + q) * S_ + kt * 32;
#pragma unroll
    for (int i = 0; i < 32; ++i)
      if (p[i]) bits |= 1u << i;
  }
  bmT[((size_t)b * (S_ / 32) + kt) * S_ + q] = bits;
}

// ---- fp32 -> bf16 convert into FRAGMENT-ORDER layout (query + Wq/Wk/Wv) ----
// frag chunk for (row, k): chunk = (row>>4)*32 + (k>>5); within chunk:
// lane = ((k>>3)&3)*16 + (row&15); element = k&7. 16B per lane-slot.
__global__ __launch_bounds__(256) void convert_kernel(
    const float* __restrict__ q, const float* __restrict__ wq,
    const float* __restrict__ wk, const float* __restrict__ wv,
    short* __restrict__ qbf, short* __restrict__ wqkv) {
  int bid = blockIdx.x;
  int t = threadIdx.x;
  const float* src;
  short* dst;
  int rowbase, seg;
  if (bid < 2048)      { src = q;  dst = qbf;  rowbase = bid * 2;          seg = -1; }
  else if (bid < 2560) { src = wq; dst = wqkv; rowbase = (bid - 2048) * 2; seg = 0; }
  else if (bid < 3072) { src = wk; dst = wqkv; rowbase = (bid - 2560) * 2; seg = 1; }
  else                 { src = wv; dst = wqkv; rowbase = (bid - 3072) * 2; seg = 2; }
  int rl = rowbase + (t >> 7);   // local row (2 rows per block)
  int k = (t & 127) * 8;
  const float* s8 = src + (size_t)rl * 1024 + k;
  f32x4 a = *(const f32x4*)s8;
  f32x4 b = *(const f32x4*)(s8 + 4);
  s16x8 r;
  r[0] = f2bf(a[0]); r[1] = f2bf(a[1]); r[2] = f2bf(a[2]); r[3] = f2bf(a[3]);
  r[4] = f2bf(b[0]); r[5] = f2bf(b[1]); r[6] = f2bf(b[2]); r[7] = f2bf(b[3]);
  int grow = (seg < 0) ? rl : (seg * 1024 + rl);
  size_t chunk = ((size_t)(grow >> 4) * 32 + (k >> 5)) * 64 +
                 ((k >> 3) & 3) * 16 + (grow & 15);
  *(s16x8*)(dst + chunk * 8) = r;
}

// ---- fp32 -> bf16 row-major convert for Wo (runs AFTER attn, into q_ws) ----
__global__ __launch_bounds__(256) void convert_wo_kernel(
    const float* __restrict__ wo, short* __restrict__ wob) {
  size_t i = ((size_t)blockIdx.x * 256 + threadIdx.x) * 8;
  f32x4 a = *(const f32x4*)(wo + i);
  f32x4 b = *(const f32x4*)(wo + i + 4);
  s16x8 r;
  r[0] = f2bf(a[0]); r[1] = f2bf(a[1]); r[2] = f2bf(a[2]); r[3] = f2bf(a[3]);
  r[4] = f2bf(b[0]); r[5] = f2bf(b[1]); r[6] = f2bf(b[2]); r[7] = f2bf(b[3]);
  *(s16x8*)(wob + i) = r;
}

// ---- fused QKV GEMM, staged: C[4096,3072] = qbf @ wqkv^T (R8, unchanged) ---
__global__ __launch_bounds__(256) void gemm_qkv_kernel(
    const short* __restrict__ A, const short* __restrict__ Bt,
    const float* __restrict__ bq, const float* __restrict__ bk,
    const float* __restrict__ bv, short* __restrict__ q_ws,
    short* __restrict__ KF, short* __restrict__ VF) {
  __shared__ short lds[8192];  // A tile 4096 shorts, B tile 4096 shorts
  const int tid = threadIdx.x;
  const int lane = tid & 63;
  const int wave = tid >> 6;
  const int l16 = lane & 15;
  const int quad = lane >> 4;
  const int mb0 = blockIdx.x * 8;
  const int nb0 = blockIdx.y * 8;
  const int m0 = blockIdx.x * 128 + (wave >> 1) * 64;
  const int n0 = blockIdx.y * 128 + (wave & 1) * 64;
  const int g = tid >> 6, c = tid & 63;

  f32x4 acc[4][4];
#pragma unroll
  for (int i = 0; i < 4; ++i)
#pragma unroll
    for (int j = 0; j < 4; ++j) acc[i][j] = (f32x4){0.f, 0.f, 0.f, 0.f};

  for (int kb = 0; kb < 32; ++kb) {
    async16(A + (((size_t)(mb0 + g) * 32 + kb) * 64 + c) * 8, lds + tid * 8);
    async16(A + (((size_t)(mb0 + g + 4) * 32 + kb) * 64 + c) * 8,
            lds + 2048 + tid * 8);
    async16(Bt + (((size_t)(nb0 + g) * 32 + kb) * 64 + c) * 8,
            lds + 4096 + tid * 8);
    async16(Bt + (((size_t)(nb0 + g + 4) * 32 + kb) * 64 + c) * 8,
            lds + 6144 + tid * 8);
    __syncthreads();
    s16x8 a[4], b[4];
#pragma unroll
    for (int i = 0; i < 4; ++i)
      a[i] = *(const s16x8*)(lds + (((wave >> 1) * 4 + i) * 64 + lane) * 8);
#pragma unroll
    for (int j = 0; j < 4; ++j)
      b[j] = *(const s16x8*)(lds + 4096 + (((wave & 1) * 4 + j) * 64 + lane) * 8);
#pragma unroll
    for (int i = 0; i < 4; ++i)
#pragma unroll
      for (int j = 0; j < 4; ++j) acc[i][j] = mfma_bf16(a[i], b[j], acc[i][j]);
    __syncthreads();
  }

#pragma unroll
  for (int i = 0; i < 4; ++i) {
#pragma unroll
    for (int j = 0; j < 4; ++j) {
#pragma unroll
      for (int r = 0; r < 4; ++r) {
        int m = m0 + i * 16 + quad * 4 + r;
        int n = n0 + j * 16 + l16;
        int seg = n >> 10, nl = n & 1023;
        float bias = (seg == 0) ? bq[nl] : ((seg == 1) ? bk[nl] : bv[nl]);
        float v = acc[i][j][r] + bias;
        if (seg == 0) v *= 0.125f;
        int bb = m >> 11, s = m & (S_ - 1);
        int hh = nl >> 6, dh = nl & 63;
        int bh = bb * H_ + hh;
        short bv16 = f2bf(v);
        if (seg == 0) {
          q_ws[((size_t)bh * S_ + s) * DH_ + dh] = bv16;
        } else if (seg == 1) {
          int kt = s >> 5, r5 = s & 31;
          int kkb = r5 >> 4, kl16 = r5 & 15;
          int kf = dh >> 5, qd = (dh >> 3) & 3, e = dh & 7;
          KF[(size_t)bh * 131072 +
             ((size_t)kt * 256 + (kkb * 2 + kf) * 64 + qd * 16 + kl16) * 8 + e] = bv16;
        } else {
          int kt = s >> 5, ko = s & 31;
          int hi = ko >> 4, qd = (ko >> 2) & 3, j4 = ko & 3;
          int nb = dh >> 4, vl16 = dh & 15, e = hi * 4 + j4;
          VF[(size_t)bh * 131072 +
             ((size_t)kt * 256 + nb * 64 + qd * 16 + vl16) * 8 + e] = bv16;
        }
      }
    }
  }
}

// ---- attention: 1024 blocks x 4 waves; staged fragment-order K/V (R8) ------
__global__ __launch_bounds__(256) void attn_kernel(
    const short* __restrict__ Q, const short* __restrict__ KF,
    const short* __restrict__ VF, const uint* __restrict__ bmT,
    short* __restrict__ ctx_out) {
  __shared__ short lds[4096];  // K tile [0:2048), V tile [2048:4096) shorts
  const int tid = threadIdx.x;
  const int lane = tid & 63;
  const int wave = tid >> 6;
  const int l16 = lane & 15;
  const int quad = lane >> 4;
  const int bid = blockIdx.x;
  const int bh = bid >> 5;
  const int qt64 = bid & 31;
  const int b = bh >> 4;
  const int h = bh & 15;
  const int qbase = qt64 * 64 + wave * 16;

  const short* Qh = Q + (size_t)bh * S_ * DH_;
  const short* KFb = KF + (size_t)bh * 131072;
  const short* VFb = VF + (size_t)bh * 131072;
  const uint* bmb = bmT + (size_t)b * (S_ / 32) * S_;

  s16x8 qf[2];
#pragma unroll
  for (int kf = 0; kf < 2; ++kf)
    qf[kf] = *(const s16x8*)(Qh + (size_t)(qbase + l16) * DH_ + kf * 32 + quad * 8);

  f32x4 ctx[4];
#pragma unroll
  for (int nb = 0; nb < 4; ++nb) ctx[nb] = (f32x4){0.f, 0.f, 0.f, 0.f};
  float ls = 0.f;

  uint w_cur = bmb[qbase + l16];
  for (int kt = 0; kt < S_ / 32; ++kt) {
    async16(KFb + (size_t)kt * 2048 + tid * 8, lds + tid * 8);
    async16(VFb + (size_t)kt * 2048 + tid * 8, lds + 2048 + tid * 8);
    int ktn = (kt < S_ / 32 - 1) ? kt + 1 : kt;
    uint w_nxt = bmb[(size_t)ktn * S_ + qbase + l16];
    __syncthreads();

    s16x8 ka[2][2], vb[4];
#pragma unroll
    for (int kb = 0; kb < 2; ++kb)
#pragma unroll
      for (int kf = 0; kf < 2; ++kf)
        ka[kb][kf] = *(const s16x8*)(lds + ((kb * 2 + kf) * 64 + lane) * 8);
#pragma unroll
    for (int nb = 0; nb < 4; ++nb)
      vb[nb] = *(const s16x8*)(lds + 2048 + (nb * 64 + lane) * 8);

    f32x4 sc[2];
#pragma unroll
    for (int kb = 0; kb < 2; ++kb) {
      f32x4 t = mfma_bf16(ka[kb][0], qf[0], (f32x4){0.f, 0.f, 0.f, 0.f});
      sc[kb] = mfma_bf16(ka[kb][1], qf[1], t);
    }

    s16x8 pa;
    float sum = 0.f;
#pragma unroll
    for (int kb = 0; kb < 2; ++kb)
#pragma unroll
      for (int r = 0; r < 4; ++r) {
        int bit = (w_cur >> (kb * 16 + quad * 4 + r)) & 1;
        float p = bit ? 0.f : __expf(sc[kb][r]);
        sum += p;
        pa[kb * 4 + r] = f2bf(p);
      }
    ls += sum;

#pragma unroll
    for (int nb = 0; nb < 4; ++nb) ctx[nb] = mfma_bf16(pa, vb[nb], ctx[nb]);
    __syncthreads();
    w_cur = w_nxt;
  }

  ls += __shfl_xor(ls, 16);
  ls += __shfl_xor(ls, 32);

#pragma unroll
  for (int r = 0; r < 4; ++r) {
    float lr = __shfl(ls, quad * 4 + r);
    float inv = 1.f / lr;
    int srow = qbase + quad * 4 + r;
#pragma unroll
    for (int nb = 0; nb < 4; ++nb) {
      int col = h * DH_ + nb * 16 + l16;
      ctx_out[(size_t)(b * S_ + srow) * D_ + col] = f2bf(ctx[nb][r] * inv);
    }
  }
}

// ---- final GEMM, staged: out[4096,1024] fp32 = ctx_bf16 @ Wo_bf16^T + bo ---
// A (ctx) and Bt (Wo) are ROW-MAJOR bf16 [rows][1024]. Staging gathers
// per-lane (16 rows x 64B contiguous per wave) so LDS lands fragment-ordered.
__global__ __launch_bounds__(256) void gemm_final_kernel(
    const short* __restrict__ A, const short* __restrict__ Bt,
    const float* __restrict__ bias, float* __restrict__ out) {
  __shared__ short lds[8192];  // A tile 4096 shorts, B tile 4096 shorts
  const int tid = threadIdx.x;
  const int lane = tid & 63;
  const int wave = tid >> 6;
  const int l16 = lane & 15;
  const int quad = lane >> 4;
  const int m0 = blockIdx.x * 128;
  const int n0 = blockIdx.y * 128;
  const int g = tid >> 6, c = tid & 63;
  const int r15 = c & 15, qd = c >> 4;

  f32x4 acc[4][4];
#pragma unroll
  for (int i = 0; i < 4; ++i)
#pragma unroll
    for (int j = 0; j < 4; ++j) acc[i][j] = (f32x4){0.f, 0.f, 0.f, 0.f};

  for (int k0 = 0; k0 < 1024; k0 += 32) {
    // A tile: 8 chunks of (16 rows x 32 k); lane slot (qd,r15) <- 16B gather
    async16(A + (size_t)(m0 + g * 16 + r15) * 1024 + k0 + qd * 8, lds + tid * 8);
    async16(A + (size_t)(m0 + (g + 4) * 16 + r15) * 1024 + k0 + qd * 8,
            lds + 2048 + tid * 8);
    async16(Bt + (size_t)(n0 + g * 16 + r15) * 1024 + k0 + qd * 8,
            lds + 4096 + tid * 8);
    async16(Bt + (size_t)(n0 + (g + 4) * 16 + r15) * 1024 + k0 + qd * 8,
            lds + 6144 + tid * 8);
    __syncthreads();
    s16x8 a[4], b[4];
#pragma unroll
    for (int i = 0; i < 4; ++i)
      a[i] = *(const s16x8*)(lds + (((wave >> 1) * 4 + i) * 64 + lane) * 8);
#pragma unroll
    for (int j = 0; j < 4; ++j)
      b[j] = *(const s16x8*)(lds + 4096 + (((wave & 1) * 4 + j) * 64 + lane) * 8);
#pragma unroll
    for (int i = 0; i < 4; ++i)
#pragma unroll
      for (int j = 0; j < 4; ++j) acc[i][j] = mfma_bf16(a[i], b[j], acc[i][j]);
    __syncthreads();
  }

  const int mw = m0 + (wave >> 1) * 64;
  const int nw = n0 + (wave & 1) * 64;
#pragma unroll
  for (int i = 0; i < 4; ++i)
#pragma unroll
    for (int j = 0; j < 4; ++j)
#pragma unroll
      for (int r = 0; r < 4; ++r) {
        int m = mw + i * 16 + quad * 4 + r;
        int n = nw + j * 16 + l16;
        out[(size_t)m * 1024 + n] = acc[i][j][r] + bias[n];
      }
}

extern "C" void kernel_launch(void* const* d_in, const int* in_sizes, int n_in,
                              void* d_out, int out_size, void* d_ws,
                              size_t ws_size, hipStream_t stream) {
  const float* query = (const float*)d_in[0];
  const void* mask = d_in[1];
  const float* Wq = (const float*)d_in[2];
  const float* bq = (const float*)d_in[3];
  const float* Wk = (const float*)d_in[4];
  const float* bk = (const float*)d_in[5];
  const float* Wv = (const float*)d_in[6];
  const float* bv = (const float*)d_in[7];
  const float* Wo = (const float*)d_in[8];
  const float* bo = (const float*)d_in[9];

  const size_t NE = (size_t)B_ * S_ * D_;  // 4194304
  short* ws_s = (short*)d_ws;
  short* q_ws = ws_s;             // [B,H,S,DH] bf16 row-major (8 MB)
  short* KF = ws_s + NE;          // K fragment-order (8 MB)
  short* VF = ws_s + 2 * NE;      // V fragment-order, PV-permuted (8 MB)
  short* ctx_ws = ws_s + 3 * NE;  // [B,S,D] bf16 row-major (8 MB)
  short* wo_bf = ws_s;            // Wo bf16 row-major (2 MB) -- ALIASES q_ws,
                                  // written only after attn (q_ws dead then)
  // scratch inside d_out (all dead before the final GEMM runs):
  short* qbf = (short*)d_out;          // [0:8M)  query bf16, fragment order
  short* wqkv = qbf + NE;              // [8:14M) Wq|Wk|Wv bf16, fragment order
  uint* bmT = (uint*)(wqkv + 3145728); // [14:15M) bitmask
  int* flag = (int*)(bmT + 262144);

  detect_mask_kernel<<<1, 64, 0, stream>>>((const uint*)mask, flag);
  build_bitmask_kernel<<<1024, 256, 0, stream>>>(mask, flag, bmT);
  convert_kernel<<<3584, 256, 0, stream>>>(query, Wq, Wk, Wv, qbf, wqkv);

  gemm_qkv_kernel<<<dim3(32, 24), 256, 0, stream>>>(qbf, wqkv, bq, bk, bv,
                                                    q_ws, KF, VF);

  attn_kernel<<<1024, 256, 0, stream>>>(q_ws, KF, VF, bmT, ctx_ws);

  convert_wo_kernel<<<512, 256, 0, stream>>>(Wo, wo_bf);

  gemm_final_kernel<<<dim3(32, 8), 256, 0, stream>>>(ctx_ws, wo_bf, bo,
                                                     (float*)d_out);
}

// Round 10
// 252.286 us; speedup vs baseline: 2.9834x; 1.0305x over previous
//
#include <hip/hip_runtime.h>

// MultiHeadedAttention: B=2, S=2048, D=1024, H=16, DH=64. fp32 in/out.
// R10: R9 + attn restructure (attn was #1: 78us, VALUBusy 68%, FETCH 70MB):
//  - 128 q-rows/block (8 waves x 16 rows, 512 thr): halves KV refetch.
//  - BK=64 (two 32-key tiles per barrier): halves barrier drains, 4 async16
//    in flight per round. Math byte-identical to the verified R9 kernel.
// gemm_qkv / gemm_final / converts unchanged (all below attn in profile).
#define B_ 2
#define S_ 2048
#define D_ 1024
#define H_ 16
#define DH_ 64

typedef float f32x4 __attribute__((ext_vector_type(4)));
typedef short s16x8 __attribute__((ext_vector_type(8)));
typedef __bf16 bf16x8 __attribute__((ext_vector_type(8)));
typedef unsigned int uint;

// ---- MFMA wrapper: tolerate either builtin signature (short8 or bf16x8) ----
template <typename T>
static __device__ auto mfma_sel(T a, T b, f32x4 c, int)
    -> decltype(__builtin_amdgcn_mfma_f32_16x16x32_bf16(a, b, c, 0, 0, 0)) {
  return __builtin_amdgcn_mfma_f32_16x16x32_bf16(a, b, c, 0, 0, 0);
}
template <typename T>
static __device__ f32x4 mfma_sel(T a, T b, f32x4 c, long) {
  return __builtin_amdgcn_mfma_f32_16x16x32_bf16(
      __builtin_bit_cast(bf16x8, a), __builtin_bit_cast(bf16x8, b), c, 0, 0, 0);
}
static __device__ __forceinline__ f32x4 mfma_bf16(s16x8 a, s16x8 b, f32x4 c) {
  return mfma_sel(a, b, c, 0);
}

static __device__ __forceinline__ short f2bf(float f) {
  unsigned u = __float_as_uint(f);
  u += 0x7fffu + ((u >> 16) & 1u);
  return (short)(u >> 16);
}

// ---- async 16B global -> LDS (per-lane GLOBAL addr ok; LDS side = base+lane*16)
static __device__ __forceinline__ void async16(const short* g, short* l) {
  __builtin_amdgcn_global_load_lds(
      (const __attribute__((address_space(1))) unsigned int*)g,
      (__attribute__((address_space(3))) unsigned int*)l, 16, 0, 0);
}

// ---- mask dtype probe: 0 = byte-bool, 1 = int32 0/1, 2 = fp32 0.0/1.0 ----
__global__ void detect_mask_kernel(const uint* __restrict__ m,
                                   int* __restrict__ flag) {
  int lane = threadIdx.x;
  bool gt1 = false, notf = false;
  for (int i = 0; i < 16; ++i) {
    uint v = m[lane * 16 + i];
    if (v > 1u) gt1 = true;
    if (v != 0u && v != 0x3F800000u) notf = true;
  }
  unsigned long long b1 = __ballot(gt1);
  unsigned long long b2 = __ballot(notf);
  if (lane == 0) {
    int f;
    if (b1 == 0ull) f = 1;
    else if (b2 == 0ull) f = 2;
    else f = 0;
    *flag = f;
  }
}

// ---- mask -> bitmask. bmT[b][kt][q] bit i = (mask[b][q][kt*32+i] != 0) ----
__global__ __launch_bounds__(256) void build_bitmask_kernel(
    const void* __restrict__ mask, const int* __restrict__ flag,
    uint* __restrict__ bmT) {
  int w = blockIdx.x * 256 + threadIdx.x;
  int b = w >> 17;
  int rem = w & 131071;
  int q = rem >> 6;
  int kt = rem & 63;
  int mty = *flag;
  uint bits = 0;
  if (mty == 0) {
    const uint* p = (const uint*)((const unsigned char*)mask +
                                  ((size_t)b * S_ + q) * S_ + (size_t)kt * 32);
#pragma unroll
    for (int i = 0; i < 8; ++i) {
      uint v = p[i];
#pragma unroll
      for (int j = 0; j < 4; ++j)
        if ((v >> (8 * j)) & 0xffu) bits |= 1u << (i * 4 + j);
    }
  } else {
    const uint* p = (const uint*)mask + ((size_t)b * S_ + q) * S_ + kt * 32;
#pragma unroll
    for (int i = 0; i < 32; ++i)
      if (p[i]) bits |= 1u << i;
  }
  bmT[((size_t)b * (S_ / 32) + kt) * S_ + q] = bits;
}

// ---- fp32 -> bf16 convert into FRAGMENT-ORDER layout (query + Wq/Wk/Wv) ----
__global__ __launch_bounds__(256) void convert_kernel(
    const float* __restrict__ q, const float* __restrict__ wq,
    const float* __restrict__ wk, const float* __restrict__ wv,
    short* __restrict__ qbf, short* __restrict__ wqkv) {
  int bid = blockIdx.x;
  int t = threadIdx.x;
  const float* src;
  short* dst;
  int rowbase, seg;
  if (bid < 2048)      { src = q;  dst = qbf;  rowbase = bid * 2;          seg = -1; }
  else if (bid < 2560) { src = wq; dst = wqkv; rowbase = (bid - 2048) * 2; seg = 0; }
  else if (bid < 3072) { src = wk; dst = wqkv; rowbase = (bid - 2560) * 2; seg = 1; }
  else                 { src = wv; dst = wqkv; rowbase = (bid - 3072) * 2; seg = 2; }
  int rl = rowbase + (t >> 7);
  int k = (t & 127) * 8;
  const float* s8 = src + (size_t)rl * 1024 + k;
  f32x4 a = *(const f32x4*)s8;
  f32x4 b = *(const f32x4*)(s8 + 4);
  s16x8 r;
  r[0] = f2bf(a[0]); r[1] = f2bf(a[1]); r[2] = f2bf(a[2]); r[3] = f2bf(a[3]);
  r[4] = f2bf(b[0]); r[5] = f2bf(b[1]); r[6] = f2bf(b[2]); r[7] = f2bf(b[3]);
  int grow = (seg < 0) ? rl : (seg * 1024 + rl);
  size_t chunk = ((size_t)(grow >> 4) * 32 + (k >> 5)) * 64 +
                 ((k >> 3) & 3) * 16 + (grow & 15);
  *(s16x8*)(dst + chunk * 8) = r;
}

// ---- fp32 -> bf16 row-major convert for Wo (runs AFTER attn, into q_ws) ----
__global__ __launch_bounds__(256) void convert_wo_kernel(
    const float* __restrict__ wo, short* __restrict__ wob) {
  size_t i = ((size_t)blockIdx.x * 256 + threadIdx.x) * 8;
  f32x4 a = *(const f32x4*)(wo + i);
  f32x4 b = *(const f32x4*)(wo + i + 4);
  s16x8 r;
  r[0] = f2bf(a[0]); r[1] = f2bf(a[1]); r[2] = f2bf(a[2]); r[3] = f2bf(a[3]);
  r[4] = f2bf(b[0]); r[5] = f2bf(b[1]); r[6] = f2bf(b[2]); r[7] = f2bf(b[3]);
  *(s16x8*)(wob + i) = r;
}

// ---- fused QKV GEMM, staged: C[4096,3072] = qbf @ wqkv^T (R8, unchanged) ---
__global__ __launch_bounds__(256) void gemm_qkv_kernel(
    const short* __restrict__ A, const short* __restrict__ Bt,
    const float* __restrict__ bq, const float* __restrict__ bk,
    const float* __restrict__ bv, short* __restrict__ q_ws,
    short* __restrict__ KF, short* __restrict__ VF) {
  __shared__ short lds[8192];
  const int tid = threadIdx.x;
  const int lane = tid & 63;
  const int wave = tid >> 6;
  const int l16 = lane & 15;
  const int quad = lane >> 4;
  const int mb0 = blockIdx.x * 8;
  const int nb0 = blockIdx.y * 8;
  const int m0 = blockIdx.x * 128 + (wave >> 1) * 64;
  const int n0 = blockIdx.y * 128 + (wave & 1) * 64;
  const int g = tid >> 6, c = tid & 63;

  f32x4 acc[4][4];
#pragma unroll
  for (int i = 0; i < 4; ++i)
#pragma unroll
    for (int j = 0; j < 4; ++j) acc[i][j] = (f32x4){0.f, 0.f, 0.f, 0.f};

  for (int kb = 0; kb < 32; ++kb) {
    async16(A + (((size_t)(mb0 + g) * 32 + kb) * 64 + c) * 8, lds + tid * 8);
    async16(A + (((size_t)(mb0 + g + 4) * 32 + kb) * 64 + c) * 8,
            lds + 2048 + tid * 8);
    async16(Bt + (((size_t)(nb0 + g) * 32 + kb) * 64 + c) * 8,
            lds + 4096 + tid * 8);
    async16(Bt + (((size_t)(nb0 + g + 4) * 32 + kb) * 64 + c) * 8,
            lds + 6144 + tid * 8);
    __syncthreads();
    s16x8 a[4], b[4];
#pragma unroll
    for (int i = 0; i < 4; ++i)
      a[i] = *(const s16x8*)(lds + (((wave >> 1) * 4 + i) * 64 + lane) * 8);
#pragma unroll
    for (int j = 0; j < 4; ++j)
      b[j] = *(const s16x8*)(lds + 4096 + (((wave & 1) * 4 + j) * 64 + lane) * 8);
#pragma unroll
    for (int i = 0; i < 4; ++i)
#pragma unroll
      for (int j = 0; j < 4; ++j) acc[i][j] = mfma_bf16(a[i], b[j], acc[i][j]);
    __syncthreads();
  }

#pragma unroll
  for (int i = 0; i < 4; ++i) {
#pragma unroll
    for (int j = 0; j < 4; ++j) {
#pragma unroll
      for (int r = 0; r < 4; ++r) {
        int m = m0 + i * 16 + quad * 4 + r;
        int n = n0 + j * 16 + l16;
        int seg = n >> 10, nl = n & 1023;
        float bias = (seg == 0) ? bq[nl] : ((seg == 1) ? bk[nl] : bv[nl]);
        float v = acc[i][j][r] + bias;
        if (seg == 0) v *= 0.125f;
        int bb = m >> 11, s = m & (S_ - 1);
        int hh = nl >> 6, dh = nl & 63;
        int bh = bb * H_ + hh;
        short bv16 = f2bf(v);
        if (seg == 0) {
          q_ws[((size_t)bh * S_ + s) * DH_ + dh] = bv16;
        } else if (seg == 1) {
          int kt = s >> 5, r5 = s & 31;
          int kkb = r5 >> 4, kl16 = r5 & 15;
          int kf = dh >> 5, qd = (dh >> 3) & 3, e = dh & 7;
          KF[(size_t)bh * 131072 +
             ((size_t)kt * 256 + (kkb * 2 + kf) * 64 + qd * 16 + kl16) * 8 + e] = bv16;
        } else {
          int kt = s >> 5, ko = s & 31;
          int hi = ko >> 4, qd = (ko >> 2) & 3, j4 = ko & 3;
          int nb = dh >> 4, vl16 = dh & 15, e = hi * 4 + j4;
          VF[(size_t)bh * 131072 +
             ((size_t)kt * 256 + nb * 64 + qd * 16 + vl16) * 8 + e] = bv16;
        }
      }
    }
  }
}

// ---- attention: 512 blocks x 8 waves (128 q-rows/block), BK=64 staging -----
__global__ void attn_kernel(
    const short* __restrict__ Q, const short* __restrict__ KF,
    const short* __restrict__ VF, const uint* __restrict__ bmT,
    short* __restrict__ ctx_out) {
  __shared__ short lds[8192];  // K 64x64 [0:4096), V 64x64 [4096:8192) shorts
  const int tid = threadIdx.x;           // [0,512)
  const int lane = tid & 63;
  const int wave = tid >> 6;             // [0,8)
  const int l16 = lane & 15;
  const int quad = lane >> 4;
  const int bid = blockIdx.x;            // [0,512)
  const int bh = bid >> 4;               // 32 bh
  const int qt128 = bid & 15;
  const int b = bh >> 4;
  const int h = bh & 15;
  const int qbase = qt128 * 128 + wave * 16;

  const short* Qh = Q + (size_t)bh * S_ * DH_;
  const short* KFb = KF + (size_t)bh * 131072;
  const short* VFb = VF + (size_t)bh * 131072;
  const uint* bmb = bmT + (size_t)b * (S_ / 32) * S_;

  s16x8 qf[2];
#pragma unroll
  for (int kf = 0; kf < 2; ++kf)
    qf[kf] = *(const s16x8*)(Qh + (size_t)(qbase + l16) * DH_ + kf * 32 + quad * 8);

  f32x4 ctx[4];
#pragma unroll
  for (int nb = 0; nb < 4; ++nb) ctx[nb] = (f32x4){0.f, 0.f, 0.f, 0.f};
  float ls = 0.f;

  for (int kt2 = 0; kt2 < S_ / 64; ++kt2) {
    // stage two 32-key tiles of K and V (4KB each side per 512 threads)
    async16(KFb + (size_t)kt2 * 4096 + tid * 8, lds + tid * 8);
    async16(VFb + (size_t)kt2 * 4096 + tid * 8, lds + 4096 + tid * 8);
    uint w[2];
    w[0] = bmb[(size_t)(2 * kt2) * S_ + qbase + l16];
    w[1] = bmb[(size_t)(2 * kt2 + 1) * S_ + qbase + l16];
    __syncthreads();

#pragma unroll
    for (int kbt = 0; kbt < 2; ++kbt) {
      s16x8 ka[2][2];
#pragma unroll
      for (int kb = 0; kb < 2; ++kb)
#pragma unroll
        for (int kf = 0; kf < 2; ++kf)
          ka[kb][kf] =
              *(const s16x8*)(lds + kbt * 2048 + ((kb * 2 + kf) * 64 + lane) * 8);

      // scores^T: C row = key(quad*4+r), col = q(l16)
      f32x4 sc[2];
#pragma unroll
      for (int kb = 0; kb < 2; ++kb) {
        f32x4 t = mfma_bf16(ka[kb][0], qf[0], (f32x4){0.f, 0.f, 0.f, 0.f});
        sc[kb] = mfma_bf16(ka[kb][1], qf[1], t);
      }

      // exp + mask + pack to PV A-operand (k_phys = (j>>2)*16 + quad*4 + (j&3))
      s16x8 pa;
      float sum = 0.f;
#pragma unroll
      for (int kb = 0; kb < 2; ++kb)
#pragma unroll
        for (int r = 0; r < 4; ++r) {
          int bit = (w[kbt] >> (kb * 16 + quad * 4 + r)) & 1;
          float p = bit ? 0.f : __expf(sc[kb][r]);
          sum += p;
          pa[kb * 4 + r] = f2bf(p);
        }
      ls += sum;

#pragma unroll
      for (int nb = 0; nb < 4; ++nb) {
        s16x8 vb =
            *(const s16x8*)(lds + 4096 + kbt * 2048 + (nb * 64 + lane) * 8);
        ctx[nb] = mfma_bf16(pa, vb, ctx[nb]);
      }
    }
    __syncthreads();
  }

  // reduce l over the 4 quads: every lane ends with row l16's total
  ls += __shfl_xor(ls, 16);
  ls += __shfl_xor(ls, 32);

  // epilogue: ctx C-layout row = q(quad*4+r), col = dh(l16); row-major out
#pragma unroll
  for (int r = 0; r < 4; ++r) {
    float lr = __shfl(ls, quad * 4 + r);
    float inv = 1.f / lr;
    int srow = qbase + quad * 4 + r;
#pragma unroll
    for (int nb = 0; nb < 4; ++nb) {
      int col = h * DH_ + nb * 16 + l16;
      ctx_out[(size_t)(b * S_ + srow) * D_ + col] = f2bf(ctx[nb][r] * inv);
    }
  }
}

// ---- final GEMM, staged: out[4096,1024] fp32 = ctx_bf16 @ Wo_bf16^T + bo ---
__global__ __launch_bounds__(256) void gemm_final_kernel(
    const short* __restrict__ A, const short* __restrict__ Bt,
    const float* __restrict__ bias, float* __restrict__ out) {
  __shared__ short lds[8192];
  const int tid = threadIdx.x;
  const int lane = tid & 63;
  const int wave = tid >> 6;
  const int l16 = lane & 15;
  const int quad = lane >> 4;
  const int m0 = blockIdx.x * 128;
  const int n0 = blockIdx.y * 128;
  const int g = tid >> 6, c = tid & 63;
  const int r15 = c & 15, qd = c >> 4;

  f32x4 acc[4][4];
#pragma unroll
  for (int i = 0; i < 4; ++i)
#pragma unroll
    for (int j = 0; j < 4; ++j) acc[i][j] = (f32x4){0.f, 0.f, 0.f, 0.f};

  for (int k0 = 0; k0 < 1024; k0 += 32) {
    async16(A + (size_t)(m0 + g * 16 + r15) * 1024 + k0 + qd * 8, lds + tid * 8);
    async16(A + (size_t)(m0 + (g + 4) * 16 + r15) * 1024 + k0 + qd * 8,
            lds + 2048 + tid * 8);
    async16(Bt + (size_t)(n0 + g * 16 + r15) * 1024 + k0 + qd * 8,
            lds + 4096 + tid * 8);
    async16(Bt + (size_t)(n0 + (g + 4) * 16 + r15) * 1024 + k0 + qd * 8,
            lds + 6144 + tid * 8);
    __syncthreads();
    s16x8 a[4], b[4];
#pragma unroll
    for (int i = 0; i < 4; ++i)
      a[i] = *(const s16x8*)(lds + (((wave >> 1) * 4 + i) * 64 + lane) * 8);
#pragma unroll
    for (int j = 0; j < 4; ++j)
      b[j] = *(const s16x8*)(lds + 4096 + (((wave & 1) * 4 + j) * 64 + lane) * 8);
#pragma unroll
    for (int i = 0; i < 4; ++i)
#pragma unroll
      for (int j = 0; j < 4; ++j) acc[i][j] = mfma_bf16(a[i], b[j], acc[i][j]);
    __syncthreads();
  }

  const int mw = m0 + (wave >> 1) * 64;
  const int nw = n0 + (wave & 1) * 64;
#pragma unroll
  for (int i = 0; i < 4; ++i)
#pragma unroll
    for (int j = 0; j < 4; ++j)
#pragma unroll
      for (int r = 0; r < 4; ++r) {
        int m = mw + i * 16 + quad * 4 + r;
        int n = nw + j * 16 + l16;
        out[(size_t)m * 1024 + n] = acc[i][j][r] + bias[n];
      }
}

extern "C" void kernel_launch(void* const* d_in, const int* in_sizes, int n_in,
                              void* d_out, int out_size, void* d_ws,
                              size_t ws_size, hipStream_t stream) {
  const float* query = (const float*)d_in[0];
  const void* mask = d_in[1];
  const float* Wq = (const float*)d_in[2];
  const float* bq = (const float*)d_in[3];
  const float* Wk = (const float*)d_in[4];
  const float* bk = (const float*)d_in[5];
  const float* Wv = (const float*)d_in[6];
  const float* bv = (const float*)d_in[7];
  const float* Wo = (const float*)d_in[8];
  const float* bo = (const float*)d_in[9];

  const size_t NE = (size_t)B_ * S_ * D_;  // 4194304
  short* ws_s = (short*)d_ws;
  short* q_ws = ws_s;             // [B,H,S,DH] bf16 row-major (8 MB)
  short* KF = ws_s + NE;          // K fragment-order (8 MB)
  short* VF = ws_s + 2 * NE;      // V fragment-order, PV-permuted (8 MB)
  short* ctx_ws = ws_s + 3 * NE;  // [B,S,D] bf16 row-major (8 MB)
  short* wo_bf = ws_s;            // Wo bf16 (2 MB) -- aliases q_ws, written
                                  // only after attn (q_ws dead then)
  // scratch inside d_out (all dead before the final GEMM runs):
  short* qbf = (short*)d_out;          // [0:8M)  query bf16, fragment order
  short* wqkv = qbf + NE;              // [8:14M) Wq|Wk|Wv bf16, fragment order
  uint* bmT = (uint*)(wqkv + 3145728); // [14:15M) bitmask
  int* flag = (int*)(bmT + 262144);

  detect_mask_kernel<<<1, 64, 0, stream>>>((const uint*)mask, flag);
  build_bitmask_kernel<<<1024, 256, 0, stream>>>(mask, flag, bmT);
  convert_kernel<<<3584, 256, 0, stream>>>(query, Wq, Wk, Wv, qbf, wqkv);

  gemm_qkv_kernel<<<dim3(32, 24), 256, 0, stream>>>(qbf, wqkv, bq, bk, bv,
                                                    q_ws, KF, VF);

  attn_kernel<<<512, 512, 0, stream>>>(q_ws, KF, VF, bmT, ctx_ws);

  convert_wo_kernel<<<512, 256, 0, stream>>>(Wo, wo_bf);

  gemm_final_kernel<<<dim3(32, 8), 256, 0, stream>>>(ctx_ws, wo_bf, bo,
                                                     (float*)d_out);
}